// Round 2
// baseline (451.917 us; speedup 1.0000x reference)
//
#include <hip/hip_runtime.h>

// EMA + gated blend, (B,L,C) = (32,4096,512) fp32.
// trend[l] = 0.7*x[l] + 0.3*trend[l-1];  out = g*x + (1-2g)*trend.
// Carry decays by 0.3/step -> parallelize the scan: each thread owns a
// CH-length chunk of L, warming the carry over an H-step halo seeded with
// x[l0-H]. Halo error ~ 0.3^(H-1) ~ 2e-6 (H=12), and it enters the output
// scaled by (1-2g) = 0 for the benched gate=0.5 -> far below the 5.4e-2
// threshold (measured absmax floor is 1.95e-3 from reference-side rounding).
//
// R1: CH 128->64 (threads 131072->262144, 8->16 waves/CU) to close the
// latency-hiding gap vs the ~6.5 TB/s fill ceiling; H 16->12; nontemporal
// stores (out is never re-read); __launch_bounds__(256,4) pins VGPR<=128.
// R2: __builtin_nontemporal_store needs a native vector type, not HIP's
// float4 struct -> store through ext_vector_type(4) alias.

constexpr int B   = 32;
constexpr int L   = 4096;
constexpr int C   = 512;
constexpr int CV  = C / 4;      // float4 groups along C = 128
constexpr int CH  = 64;         // chunk length along L
constexpr int NCH = L / CH;     // 64 chunks
constexpr int H   = 12;         // halo warm-up length
constexpr float ALPHA = 0.7f;

typedef float f32x4 __attribute__((ext_vector_type(4)));

__device__ __forceinline__ void nt_store4(float4* p, const float4& v) {
    f32x4 w = {v.x, v.y, v.z, v.w};
    __builtin_nontemporal_store(w, reinterpret_cast<f32x4*>(p));
}

__device__ __forceinline__ float4 ema_step(float4 t, float4 xv, float a, float na) {
    float4 r;
    r.x = fmaf(a, xv.x, na * t.x);
    r.y = fmaf(a, xv.y, na * t.y);
    r.z = fmaf(a, xv.z, na * t.z);
    r.w = fmaf(a, xv.w, na * t.w);
    return r;
}

__global__ __launch_bounds__(256, 4) void STAR_47605417509306_kernel(
        const float4* __restrict__ x, const float* __restrict__ gate,
        float4* __restrict__ out) {
    const int tid   = blockIdx.x * blockDim.x + threadIdx.x;
    const int c4    = tid & (CV - 1);          // fastest-varying -> coalesced
    const int rest  = tid / CV;
    const int chunk = rest & (NCH - 1);
    const int b     = rest / NCH;

    float g = gate[0];
    g = fminf(fmaxf(g, 0.0f), 1.0f);
    const float a  = ALPHA;
    const float na = 1.0f - ALPHA;
    const float c2 = 1.0f - 2.0f * g;          // out = g*x + (1-2g)*t

    const int base = (b * L) * CV + c4;        // float4 index of (b, l=0, c4)
    const int l0   = chunk * CH;

    float4 t;
    int lstart;
    if (chunk == 0) {
        // Exact start: t_0 = x_0, and l=0 produces an output.
        t = x[base];
        float4 o;
        o.x = fmaf(g, t.x, c2 * t.x);
        o.y = fmaf(g, t.y, c2 * t.y);
        o.z = fmaf(g, t.z, c2 * t.z);
        o.w = fmaf(g, t.w, c2 * t.w);
        nt_store4(&out[base], o);
        lstart = 1;
    } else {
        // Halo warm-up: seed with x[l0-H], run H-1 recurrence steps.
        t = x[base + (l0 - H) * CV];
#pragma unroll
        for (int l = l0 - H + 1; l < l0; ++l) {
            float4 xv = x[base + l * CV];
            t = ema_step(t, xv, a, na);
        }
        lstart = l0;
    }

#pragma unroll 8
    for (int l = lstart; l < l0 + CH; ++l) {
        float4 xv = x[base + l * CV];
        t = ema_step(t, xv, a, na);
        float4 o;
        o.x = fmaf(g, xv.x, c2 * t.x);
        o.y = fmaf(g, xv.y, c2 * t.y);
        o.z = fmaf(g, xv.z, c2 * t.z);
        o.w = fmaf(g, xv.w, c2 * t.w);
        nt_store4(&out[base + l * CV], o);
    }
}

extern "C" void kernel_launch(void* const* d_in, const int* in_sizes, int n_in,
                              void* d_out, int out_size, void* d_ws, size_t ws_size,
                              hipStream_t stream) {
    const float4* x    = (const float4*)d_in[0];
    const float*  gate = (const float*)d_in[1];
    float4* out        = (float4*)d_out;

    const int total_threads = B * NCH * CV;    // 262144
    const int block = 256;
    const int grid  = total_threads / block;   // 1024
    STAR_47605417509306_kernel<<<grid, block, 0, stream>>>(x, gate, out);
}